// Round 4
// baseline (393.290 us; speedup 1.0000x reference)
//
#include <hip/hip_runtime.h>
#include <cstddef>

// ---------------- degree ----------------
__global__ void k_degree(const int* __restrict__ dst, int* __restrict__ cnt, int E) {
    int e = blockIdx.x * 256 + threadIdx.x;
    if (e < E) atomicAdd(&cnt[dst[e]], 1);
}

// ---------------- exclusive scan of cnt -> rowptr (3 passes) ----------------
__global__ void k_scan1(const int* __restrict__ cnt, int* __restrict__ rowptr,
                        int* __restrict__ bsum, int N) {
    __shared__ int s[256];
    int i = blockIdx.x * 256 + threadIdx.x;
    int v = (i < N) ? cnt[i] : 0;
    s[threadIdx.x] = v;
    __syncthreads();
    for (int off = 1; off < 256; off <<= 1) {
        int t = (threadIdx.x >= off) ? s[threadIdx.x - off] : 0;
        __syncthreads();
        s[threadIdx.x] += t;
        __syncthreads();
    }
    if (i < N) rowptr[i] = s[threadIdx.x];          // inclusive, per-block
    if (threadIdx.x == 255) bsum[blockIdx.x] = s[255];
}

// scan across block sums + (folded) per-graph inverse counts via binary search
__global__ void k_scan2(int* __restrict__ bsum, int nb,
                        const int* __restrict__ batch, float* __restrict__ invcnt, int N) {
    __shared__ int s[256];
    __shared__ int carry;
    if (threadIdx.x == 0) carry = 0;
    __syncthreads();
    for (int base = 0; base < nb; base += 256) {
        int i = base + threadIdx.x;
        int v = (i < nb) ? bsum[i] : 0;
        s[threadIdx.x] = v;
        __syncthreads();
        for (int off = 1; off < 256; off <<= 1) {
            int t = (threadIdx.x >= off) ? s[threadIdx.x - off] : 0;
            __syncthreads();
            s[threadIdx.x] += t;
            __syncthreads();
        }
        if (i < nb) bsum[i] = s[threadIdx.x] + carry;
        __syncthreads();
        if (threadIdx.x == 0) carry += s[255];
        __syncthreads();
    }
    // folded k_gcount (no barriers below this point)
    int g = threadIdx.x;
    if (g < 128) {
        int lo = 0, hi = N;
        while (lo < hi) { int m = (lo + hi) >> 1; if (batch[m] < g) lo = m + 1; else hi = m; }
        int st = lo;
        lo = st; hi = N;
        while (lo < hi) { int m = (lo + hi) >> 1; if (batch[m] <= g) lo = m + 1; else hi = m; }
        invcnt[g] = 1.0f / fmaxf((float)(lo - st), 1.0f);
    }
}

// finalize exclusive scan + (folded) dinv
__global__ void k_scan3(int* __restrict__ rowptr, const int* __restrict__ cnt,
                        const int* __restrict__ bsum, float* __restrict__ dinv, int N) {
    int i = blockIdx.x * 256 + threadIdx.x;
    if (i >= N) return;
    int c = cnt[i];
    int boff = (blockIdx.x > 0) ? bsum[blockIdx.x - 1] : 0;
    rowptr[i] = rowptr[i] - c + boff;               // exclusive scan
    dinv[i] = rsqrtf((float)c + 1.0f);
}

// ---------------- scatter edges into CSR by dst ----------------
__global__ void k_scatter(const int* __restrict__ src, const int* __restrict__ dst,
                          const int* __restrict__ rowptr, int* __restrict__ fill,
                          int* __restrict__ csr_src, int E) {
    int e = blockIdx.x * 256 + threadIdx.x;
    if (e >= E) return;
    int d = dst[e];
    int pos = rowptr[d] + atomicAdd(&fill[d], 1);
    csr_src[pos] = src[e];
}

// ---------------- GEMM: Y[N,128] = X[N,128] @ W[128,128] ----------------
// Persistent blocks, 64-row tile, double-buffered X staged through registers
// (issue loads early, ds_write late). Thread computes 4 rows x 8 cols.
__global__ __launch_bounds__(256) void k_gemm64(const float* __restrict__ X,
                                                const float* __restrict__ W,
                                                float* __restrict__ Y, int N) {
    __shared__ float Ws[128 * 128];
    __shared__ float Xs[2][64 * 128];
    const int tid = threadIdx.x;
    const int ntiles = (N + 63) >> 6;
    const long maxg4 = (long)N * 32;

    const float4* W4 = (const float4*)W;
    float4* Ws4 = (float4*)Ws;
    #pragma unroll
    for (int i = 0; i < 16; ++i) Ws4[tid + i * 256] = W4[tid + i * 256];

    int t = blockIdx.x;
    if (t >= ntiles) { return; }

    float4 st[8];
    {   // stage tile t into Xs[0]
        long base4 = (long)t * 2048;
        #pragma unroll
        for (int i = 0; i < 8; ++i) {
            long g4 = base4 + i * 256 + tid;
            if (g4 >= maxg4) g4 = 0;           // clamp (rows >= N discarded at store)
            st[i] = ((const float4*)X)[g4];
        }
        float4* xs4 = (float4*)Xs[0];
        #pragma unroll
        for (int i = 0; i < 8; ++i) xs4[i * 256 + tid] = st[i];
    }
    __syncthreads();

    const int r0 = (tid >> 4) * 4;   // 16 row-groups x 4 rows
    const int c0 = (tid & 15) * 8;   // 16 col-groups x 8 cols
    int cur = 0;
    while (true) {
        int tn = t + gridDim.x;
        bool has_next = (tn < ntiles);
        if (has_next) {               // T14: issue next tile's loads before compute
            long base4 = (long)tn * 2048;
            #pragma unroll
            for (int i = 0; i < 8; ++i) {
                long g4 = base4 + i * 256 + tid;
                if (g4 >= maxg4) g4 = 0;
                st[i] = ((const float4*)X)[g4];
            }
        }
        float acc[4][8];
        #pragma unroll
        for (int i = 0; i < 4; ++i)
            #pragma unroll
            for (int j = 0; j < 8; ++j) acc[i][j] = 0.0f;

        const float* xb = Xs[cur];
        #pragma unroll 2
        for (int k = 0; k < 128; ++k) {
            float4 w0 = *(const float4*)&Ws[k * 128 + c0];
            float4 w1 = *(const float4*)&Ws[k * 128 + c0 + 4];
            #pragma unroll
            for (int i = 0; i < 4; ++i) {
                float xv = xb[(r0 + i) * 128 + k];
                acc[i][0] += xv * w0.x; acc[i][1] += xv * w0.y;
                acc[i][2] += xv * w0.z; acc[i][3] += xv * w0.w;
                acc[i][4] += xv * w1.x; acc[i][5] += xv * w1.y;
                acc[i][6] += xv * w1.z; acc[i][7] += xv * w1.w;
            }
        }
        long row0 = (long)t * 64;
        #pragma unroll
        for (int i = 0; i < 4; ++i) {
            long r = row0 + r0 + i;
            if (r < N) {
                *(float4*)&Y[r * 128 + c0]     = make_float4(acc[i][0], acc[i][1], acc[i][2], acc[i][3]);
                *(float4*)&Y[r * 128 + c0 + 4] = make_float4(acc[i][4], acc[i][5], acc[i][6], acc[i][7]);
            }
        }
        if (!has_next) break;
        __syncthreads();              // all waves done reading Xs[cur^1] (prev iter)
        float4* xs4 = (float4*)Xs[cur ^ 1];
        #pragma unroll
        for (int i = 0; i < 8; ++i) xs4[i * 256 + tid] = st[i];
        __syncthreads();
        cur ^= 1;
        t = tn;
    }
}

// ---------------- fused pull aggregation + self-loop + bias + relu ----------
// half-wave (32 lanes) per node; lane owns a float4 of the 128-wide row.
__global__ __launch_bounds__(256) void k_gcn_agg(const float* __restrict__ T,
                                                 const int* __restrict__ csr_src,
                                                 const int* __restrict__ rowptr,
                                                 const int* __restrict__ cnt,
                                                 const float* __restrict__ dinv,
                                                 const float* __restrict__ b,
                                                 float* __restrict__ OUT, int N) {
    int node = blockIdx.x * 8 + (threadIdx.x >> 5);
    if (node >= N) return;
    int lane = threadIdx.x & 31;
    int start = rowptr[node];
    int len = cnt[node];
    float dn = dinv[node];

    const float4* T4 = (const float4*)T;
    float4 self = T4[(size_t)node * 32 + lane];
    float sw = dn * dn;
    float ax = self.x * sw, ay = self.y * sw, az = self.z * sw, aw = self.w * sw;

    int j = 0;
    for (; j + 3 < len; j += 4) {
        int s0 = csr_src[start + j + 0];
        int s1 = csr_src[start + j + 1];
        int s2 = csr_src[start + j + 2];
        int s3 = csr_src[start + j + 3];
        float w0 = dinv[s0] * dn;
        float w1 = dinv[s1] * dn;
        float w2 = dinv[s2] * dn;
        float w3 = dinv[s3] * dn;
        float4 v0 = T4[(size_t)s0 * 32 + lane];
        float4 v1 = T4[(size_t)s1 * 32 + lane];
        float4 v2 = T4[(size_t)s2 * 32 + lane];
        float4 v3 = T4[(size_t)s3 * 32 + lane];
        ax += w0 * v0.x + w1 * v1.x + w2 * v2.x + w3 * v3.x;
        ay += w0 * v0.y + w1 * v1.y + w2 * v2.y + w3 * v3.y;
        az += w0 * v0.z + w1 * v1.z + w2 * v2.z + w3 * v3.z;
        aw += w0 * v0.w + w1 * v1.w + w2 * v2.w + w3 * v3.w;
    }
    for (; j < len; ++j) {
        int s = csr_src[start + j];
        float w = dinv[s] * dn;
        float4 v = T4[(size_t)s * 32 + lane];
        ax += w * v.x; ay += w * v.y; az += w * v.z; aw += w * v.w;
    }

    float4 bias = ((const float4*)b)[lane];
    float4 o = make_float4(fmaxf(ax + bias.x, 0.0f), fmaxf(ay + bias.y, 0.0f),
                           fmaxf(az + bias.z, 0.0f), fmaxf(aw + bias.w, 0.0f));
    ((float4*)OUT)[(size_t)node * 32 + lane] = o;
}

// ---------------- pooling: chunked segment-sum, few atomics --------
__global__ __launch_bounds__(128) void k_pool3(const float* __restrict__ H,
                                               const int* __restrict__ batch,
                                               const float* __restrict__ invcnt,
                                               float* __restrict__ pooled, int N) {
    int t = threadIdx.x;          // feature column
    int n0 = blockIdx.x * 128;
    if (n0 >= N) return;
    int n1 = min(n0 + 128, N);
    int curg = batch[n0];
    float acc = 0.0f;
    for (int n = n0; n < n1; ++n) {
        int g = batch[n];
        if (g != curg) {
            atomicAdd(&pooled[curg * 128 + t], acc * invcnt[curg]);
            acc = 0.0f;
            curg = g;
        }
        acc += H[(size_t)n * 128 + t];
    }
    atomicAdd(&pooled[curg * 128 + t], acc * invcnt[curg]);
}

// ---------------- fc1: Z[128,64] = relu(pooled @ W + b) ----------------
__global__ void k_fc1(const float* __restrict__ pooled, const float* __restrict__ W,
                      const float* __restrict__ b, float* __restrict__ Z) {
    int g = blockIdx.x, c = threadIdx.x;  // 128 blocks x 64 threads
    float acc = b[c];
    for (int k = 0; k < 128; ++k)
        acc += pooled[g * 128 + k] * W[k * 64 + c];
    Z[g * 64 + c] = fmaxf(acc, 0.0f);
}

// ---------------- BN (training stats) + final linear ----------------
__global__ void k_bn_out(const float* __restrict__ Z, const float* __restrict__ gamma,
                         const float* __restrict__ beta, const float* __restrict__ w3,
                         const float* __restrict__ b3, float* __restrict__ out) {
    __shared__ float mu[64], rs[64], gw[64], bw[64];
    int t = threadIdx.x;
    if (t < 64) {
        float s = 0.f, ss = 0.f;
        for (int g = 0; g < 128; ++g) {
            float v = Z[g * 64 + t];
            s += v; ss += v * v;
        }
        float m = s * (1.0f / 128.0f);
        float var = ss * (1.0f / 128.0f) - m * m;
        mu[t] = m;
        rs[t] = rsqrtf(var + 1e-5f);
        gw[t] = gamma[t];
        bw[t] = beta[t];
    }
    __syncthreads();
    if (t < 128) {
        float acc = b3[0];
        for (int c = 0; c < 64; ++c)
            acc += ((Z[t * 64 + c] - mu[c]) * rs[c] * gw[c] + bw[c]) * w3[c];
        out[t] = acc;
    }
}

extern "C" void kernel_launch(void* const* d_in, const int* in_sizes, int n_in,
                              void* d_out, int out_size, void* d_ws, size_t ws_size,
                              hipStream_t stream) {
    const float* x    = (const float*)d_in[0];
    const int* eidx   = (const int*)d_in[1];
    const int* batch  = (const int*)d_in[2];
    const float* W1   = (const float*)d_in[3];
    const float* b1   = (const float*)d_in[4];
    const float* W2   = (const float*)d_in[5];
    const float* b2   = (const float*)d_in[6];
    const float* fcW1 = (const float*)d_in[7];
    const float* fcb1 = (const float*)d_in[8];
    const float* gamma= (const float*)d_in[9];
    const float* beta = (const float*)d_in[10];
    const float* fcW3 = (const float*)d_in[11];
    const float* fcb3 = (const float*)d_in[12];
    float* out = (float*)d_out;

    const int N = in_sizes[0] / 128;
    const int E = in_sizes[1] / 2;
    const int* src = eidx;
    const int* dst = eidx + E;

    // workspace layout
    char* ws = (char*)d_ws;
    float* bufA   = (float*)ws;                        // N*128
    float* bufB   = bufA + (size_t)N * 128;            // N*128
    int*   cnt    = (int*)(bufB + (size_t)N * 128);    // N
    float* dinv   = (float*)(cnt + N);                 // N
    int*   rowptr = (int*)(dinv + N);                  // N
    int*   fill   = rowptr + N;                        // N
    int*   bsum   = fill + N;                          // 1024
    int*   csr_src= bsum + 1024;                       // E
    float* pooled = (float*)(csr_src + E);             // 128*128
    float* Z      = pooled + 128 * 128;                // 128*64
    float* invcnt = Z + 128 * 64;                      // 128

    const int TB = 256;
    int nblk = (N + TB - 1) / TB;
    int eblk = (E + TB - 1) / TB;
    int agg_blocks  = (N + 7) / 8;
    int pool_blocks = (N + 127) / 128;

    hipMemsetAsync(cnt, 0, (size_t)N * sizeof(int), stream);
    hipMemsetAsync(fill, 0, (size_t)N * sizeof(int), stream);
    hipMemsetAsync(pooled, 0, 128 * 128 * sizeof(float), stream);

    // CSR build (+ folded dinv, invcnt)
    k_degree<<<eblk, TB, 0, stream>>>(dst, cnt, E);
    k_scan1<<<nblk, TB, 0, stream>>>(cnt, rowptr, bsum, N);
    k_scan2<<<1, TB, 0, stream>>>(bsum, nblk, batch, invcnt, N);
    k_scan3<<<nblk, TB, 0, stream>>>(rowptr, cnt, bsum, dinv, N);
    k_scatter<<<eblk, TB, 0, stream>>>(src, dst, rowptr, fill, csr_src, E);

    // layer 1
    k_gemm64<<<256, TB, 0, stream>>>(x, W1, bufA, N);
    k_gcn_agg<<<agg_blocks, TB, 0, stream>>>(bufA, csr_src, rowptr, cnt, dinv, b1, bufB, N);

    // layer 2
    k_gemm64<<<256, TB, 0, stream>>>(bufB, W2, bufA, N);
    k_gcn_agg<<<agg_blocks, TB, 0, stream>>>(bufA, csr_src, rowptr, cnt, dinv, b2, bufB, N);

    // pool + head
    k_pool3<<<pool_blocks, 128, 0, stream>>>(bufB, batch, invcnt, pooled, N);
    k_fc1<<<128, 64, 0, stream>>>(pooled, fcW1, fcb1, Z);
    k_bn_out<<<1, 256, 0, stream>>>(Z, gamma, beta, fcW3, fcb3, out);
}

// Round 5
// 341.245 us; speedup vs baseline: 1.1525x; 1.1525x over previous
//
#include <hip/hip_runtime.h>
#include <cstddef>

// ---------------- degree ----------------
__global__ void k_degree(const int* __restrict__ dst, int* __restrict__ cnt, int E) {
    int e = blockIdx.x * 256 + threadIdx.x;
    if (e < E) atomicAdd(&cnt[dst[e]], 1);
}

// ---------------- exclusive scan of cnt -> rowptr (3 passes) ----------------
__global__ void k_scan1(const int* __restrict__ cnt, int* __restrict__ rowptr,
                        int* __restrict__ bsum, int N) {
    __shared__ int s[256];
    int i = blockIdx.x * 256 + threadIdx.x;
    int v = (i < N) ? cnt[i] : 0;
    s[threadIdx.x] = v;
    __syncthreads();
    for (int off = 1; off < 256; off <<= 1) {
        int t = (threadIdx.x >= off) ? s[threadIdx.x - off] : 0;
        __syncthreads();
        s[threadIdx.x] += t;
        __syncthreads();
    }
    if (i < N) rowptr[i] = s[threadIdx.x];          // inclusive, per-block
    if (threadIdx.x == 255) bsum[blockIdx.x] = s[255];
}

// scan across block sums + (folded) per-graph inverse counts via binary search
__global__ void k_scan2(int* __restrict__ bsum, int nb,
                        const int* __restrict__ batch, float* __restrict__ invcnt, int N) {
    __shared__ int s[256];
    __shared__ int carry;
    if (threadIdx.x == 0) carry = 0;
    __syncthreads();
    for (int base = 0; base < nb; base += 256) {
        int i = base + threadIdx.x;
        int v = (i < nb) ? bsum[i] : 0;
        s[threadIdx.x] = v;
        __syncthreads();
        for (int off = 1; off < 256; off <<= 1) {
            int t = (threadIdx.x >= off) ? s[threadIdx.x - off] : 0;
            __syncthreads();
            s[threadIdx.x] += t;
            __syncthreads();
        }
        if (i < nb) bsum[i] = s[threadIdx.x] + carry;
        __syncthreads();
        if (threadIdx.x == 0) carry += s[255];
        __syncthreads();
    }
    int g = threadIdx.x;
    if (g < 128) {
        int lo = 0, hi = N;
        while (lo < hi) { int m = (lo + hi) >> 1; if (batch[m] < g) lo = m + 1; else hi = m; }
        int st = lo;
        lo = st; hi = N;
        while (lo < hi) { int m = (lo + hi) >> 1; if (batch[m] <= g) lo = m + 1; else hi = m; }
        invcnt[g] = 1.0f / fmaxf((float)(lo - st), 1.0f);
    }
}

// finalize exclusive scan + (folded) dinv
__global__ void k_scan3(int* __restrict__ rowptr, const int* __restrict__ cnt,
                        const int* __restrict__ bsum, float* __restrict__ dinv, int N) {
    int i = blockIdx.x * 256 + threadIdx.x;
    if (i >= N) return;
    int c = cnt[i];
    int boff = (blockIdx.x > 0) ? bsum[blockIdx.x - 1] : 0;
    rowptr[i] = rowptr[i] - c + boff;               // exclusive scan
    dinv[i] = rsqrtf((float)c + 1.0f);
}

// ---------------- scatter edges into CSR by dst ----------------
__global__ void k_scatter(const int* __restrict__ src, const int* __restrict__ dst,
                          const int* __restrict__ rowptr, int* __restrict__ fill,
                          int* __restrict__ csr_src, int E) {
    int e = blockIdx.x * 256 + threadIdx.x;
    if (e >= E) return;
    int d = dst[e];
    int pos = rowptr[d] + atomicAdd(&fill[d], 1);
    csr_src[pos] = src[e];
}

// ---------------- GEMM: Y[N,128] = X[N,128] @ W[128,128] ----------------
// 64-row tile. X staged TRANSPOSED in LDS (XsT[k][row], pad 68 -> conflict-free
// b128 reads). W staged in two 64-row halves (32 KB) -> total LDS 66 KB,
// 2 blocks/CU. Thread computes 4 rows x 8 cols; per-k: 3 ds_read_b128 + 32 FMA.
__global__ __launch_bounds__(256) void k_gemmT(const float* __restrict__ X,
                                               const float* __restrict__ W,
                                               float* __restrict__ Y, int N) {
    __shared__ float Ws[64 * 128];    // 32 KB (one k-half)
    __shared__ float XsT[128 * 68];   // 34 KB transposed X tile
    const int tid = threadIdx.x;
    const long row0 = (long)blockIdx.x * 64;

    // stage X transposed: lane owns row = tid&63 -> LDS writes 2-way max
    {
        int row = tid & 63;
        int q = tid >> 6;             // 0..3
        long grow = row0 + row;
        if (grow >= N) grow = N - 1;  // clamped dup read; stores guarded later
        const float4* Xr = (const float4*)(X + grow * 128);
        float4 v[8];
        #pragma unroll
        for (int i = 0; i < 8; ++i) v[i] = Xr[q + 4 * i];
        #pragma unroll
        for (int i = 0; i < 8; ++i) {
            int c4 = q + 4 * i;
            XsT[(4 * c4 + 0) * 68 + row] = v[i].x;
            XsT[(4 * c4 + 1) * 68 + row] = v[i].y;
            XsT[(4 * c4 + 2) * 68 + row] = v[i].z;
            XsT[(4 * c4 + 3) * 68 + row] = v[i].w;
        }
    }

    const int r0 = (tid >> 4) * 4;   // 16 groups x 4 rows = 64
    const int c0 = (tid & 15) * 8;   // 16 groups x 8 cols = 128
    float acc[4][8] = {};

    for (int kk = 0; kk < 128; kk += 64) {
        __syncthreads();             // X staged (iter 0) / prev half computed
        {   // stage W rows kk..kk+63 (coalesced, linear writes)
            const float4* Wh = (const float4*)(W + kk * 128);
            float4* Ws4 = (float4*)Ws;
            #pragma unroll
            for (int i = 0; i < 8; ++i) Ws4[tid + i * 256] = Wh[tid + i * 256];
        }
        __syncthreads();
        #pragma unroll 4
        for (int k = 0; k < 64; ++k) {
            float4 xr = *(const float4*)&XsT[(kk + k) * 68 + r0];
            float4 w0 = *(const float4*)&Ws[k * 128 + c0];
            float4 w1 = *(const float4*)&Ws[k * 128 + c0 + 4];
            float xv[4] = {xr.x, xr.y, xr.z, xr.w};
            #pragma unroll
            for (int i = 0; i < 4; ++i) {
                acc[i][0] += xv[i] * w0.x; acc[i][1] += xv[i] * w0.y;
                acc[i][2] += xv[i] * w0.z; acc[i][3] += xv[i] * w0.w;
                acc[i][4] += xv[i] * w1.x; acc[i][5] += xv[i] * w1.y;
                acc[i][6] += xv[i] * w1.z; acc[i][7] += xv[i] * w1.w;
            }
        }
    }

    #pragma unroll
    for (int i = 0; i < 4; ++i) {
        long r = row0 + r0 + i;
        if (r < N) {
            *(float4*)&Y[r * 128 + c0]     = make_float4(acc[i][0], acc[i][1], acc[i][2], acc[i][3]);
            *(float4*)&Y[r * 128 + c0 + 4] = make_float4(acc[i][4], acc[i][5], acc[i][6], acc[i][7]);
        }
    }
}

// ---------------- fused pull aggregation + self-loop + bias + relu ----------
// half-wave (32 lanes) per node; lane owns a float4; 8-deep gather unroll.
__global__ __launch_bounds__(256) void k_gcn_agg(const float* __restrict__ T,
                                                 const int* __restrict__ csr_src,
                                                 const int* __restrict__ rowptr,
                                                 const int* __restrict__ cnt,
                                                 const float* __restrict__ dinv,
                                                 const float* __restrict__ b,
                                                 float* __restrict__ OUT, int N) {
    int node = blockIdx.x * 8 + (threadIdx.x >> 5);
    if (node >= N) return;
    int lane = threadIdx.x & 31;
    int start = rowptr[node];
    int len = cnt[node];
    float dn = dinv[node];

    const float4* T4 = (const float4*)T;
    float4 self = T4[(size_t)node * 32 + lane];
    float sw = dn * dn;
    float ax = self.x * sw, ay = self.y * sw, az = self.z * sw, aw = self.w * sw;

    int j = 0;
    for (; j + 7 < len; j += 8) {
        int s[8];
        #pragma unroll
        for (int u = 0; u < 8; ++u) s[u] = csr_src[start + j + u];
        float w[8];
        #pragma unroll
        for (int u = 0; u < 8; ++u) w[u] = dinv[s[u]] * dn;
        float4 v[8];
        #pragma unroll
        for (int u = 0; u < 8; ++u) v[u] = T4[(size_t)s[u] * 32 + lane];
        #pragma unroll
        for (int u = 0; u < 8; ++u) {
            ax += w[u] * v[u].x; ay += w[u] * v[u].y;
            az += w[u] * v[u].z; aw += w[u] * v[u].w;
        }
    }
    for (; j < len; ++j) {
        int s = csr_src[start + j];
        float w = dinv[s] * dn;
        float4 v = T4[(size_t)s * 32 + lane];
        ax += w * v.x; ay += w * v.y; az += w * v.z; aw += w * v.w;
    }

    float4 bias = ((const float4*)b)[lane];
    float4 o = make_float4(fmaxf(ax + bias.x, 0.0f), fmaxf(ay + bias.y, 0.0f),
                           fmaxf(az + bias.z, 0.0f), fmaxf(aw + bias.w, 0.0f));
    ((float4*)OUT)[(size_t)node * 32 + lane] = o;
}

// ---------------- pooling: chunked segment-sum, few atomics --------
__global__ __launch_bounds__(128) void k_pool3(const float* __restrict__ H,
                                               const int* __restrict__ batch,
                                               const float* __restrict__ invcnt,
                                               float* __restrict__ pooled, int N) {
    int t = threadIdx.x;          // feature column
    int n0 = blockIdx.x * 128;
    if (n0 >= N) return;
    int n1 = min(n0 + 128, N);
    int curg = batch[n0];
    float acc = 0.0f;
    for (int n = n0; n < n1; ++n) {
        int g = batch[n];
        if (g != curg) {
            atomicAdd(&pooled[curg * 128 + t], acc * invcnt[curg]);
            acc = 0.0f;
            curg = g;
        }
        acc += H[(size_t)n * 128 + t];
    }
    atomicAdd(&pooled[curg * 128 + t], acc * invcnt[curg]);
}

// ---------------- fc1: Z[128,64] = relu(pooled @ W + b) ----------------
__global__ void k_fc1(const float* __restrict__ pooled, const float* __restrict__ W,
                      const float* __restrict__ b, float* __restrict__ Z) {
    int g = blockIdx.x, c = threadIdx.x;  // 128 blocks x 64 threads
    float acc = b[c];
    for (int k = 0; k < 128; ++k)
        acc += pooled[g * 128 + k] * W[k * 64 + c];
    Z[g * 64 + c] = fmaxf(acc, 0.0f);
}

// ---------------- BN (training stats) + final linear ----------------
__global__ void k_bn_out(const float* __restrict__ Z, const float* __restrict__ gamma,
                         const float* __restrict__ beta, const float* __restrict__ w3,
                         const float* __restrict__ b3, float* __restrict__ out) {
    __shared__ float mu[64], rs[64], gw[64], bw[64];
    int t = threadIdx.x;
    if (t < 64) {
        float s = 0.f, ss = 0.f;
        for (int g = 0; g < 128; ++g) {
            float v = Z[g * 64 + t];
            s += v; ss += v * v;
        }
        float m = s * (1.0f / 128.0f);
        float var = ss * (1.0f / 128.0f) - m * m;
        mu[t] = m;
        rs[t] = rsqrtf(var + 1e-5f);
        gw[t] = gamma[t];
        bw[t] = beta[t];
    }
    __syncthreads();
    if (t < 128) {
        float acc = b3[0];
        for (int c = 0; c < 64; ++c)
            acc += ((Z[t * 64 + c] - mu[c]) * rs[c] * gw[c] + bw[c]) * w3[c];
        out[t] = acc;
    }
}

extern "C" void kernel_launch(void* const* d_in, const int* in_sizes, int n_in,
                              void* d_out, int out_size, void* d_ws, size_t ws_size,
                              hipStream_t stream) {
    const float* x    = (const float*)d_in[0];
    const int* eidx   = (const int*)d_in[1];
    const int* batch  = (const int*)d_in[2];
    const float* W1   = (const float*)d_in[3];
    const float* b1   = (const float*)d_in[4];
    const float* W2   = (const float*)d_in[5];
    const float* b2   = (const float*)d_in[6];
    const float* fcW1 = (const float*)d_in[7];
    const float* fcb1 = (const float*)d_in[8];
    const float* gamma= (const float*)d_in[9];
    const float* beta = (const float*)d_in[10];
    const float* fcW3 = (const float*)d_in[11];
    const float* fcb3 = (const float*)d_in[12];
    float* out = (float*)d_out;

    const int N = in_sizes[0] / 128;
    const int E = in_sizes[1] / 2;
    const int* src = eidx;
    const int* dst = eidx + E;

    // workspace layout
    char* ws = (char*)d_ws;
    float* bufA   = (float*)ws;                        // N*128
    float* bufB   = bufA + (size_t)N * 128;            // N*128
    int*   cnt    = (int*)(bufB + (size_t)N * 128);    // N
    float* dinv   = (float*)(cnt + N);                 // N
    int*   rowptr = (int*)(dinv + N);                  // N
    int*   fill   = rowptr + N;                        // N
    int*   bsum   = fill + N;                          // 1024
    int*   csr_src= bsum + 1024;                       // E
    float* pooled = (float*)(csr_src + E);             // 128*128
    float* Z      = pooled + 128 * 128;                // 128*64
    float* invcnt = Z + 128 * 64;                      // 128

    const int TB = 256;
    int nblk = (N + TB - 1) / TB;
    int eblk = (E + TB - 1) / TB;
    int gemm_blocks = (N + 63) / 64;
    int agg_blocks  = (N + 7) / 8;
    int pool_blocks = (N + 127) / 128;

    hipMemsetAsync(cnt, 0, (size_t)N * sizeof(int), stream);
    hipMemsetAsync(fill, 0, (size_t)N * sizeof(int), stream);
    hipMemsetAsync(pooled, 0, 128 * 128 * sizeof(float), stream);

    // CSR build (+ folded dinv, invcnt)
    k_degree<<<eblk, TB, 0, stream>>>(dst, cnt, E);
    k_scan1<<<nblk, TB, 0, stream>>>(cnt, rowptr, bsum, N);
    k_scan2<<<1, TB, 0, stream>>>(bsum, nblk, batch, invcnt, N);
    k_scan3<<<nblk, TB, 0, stream>>>(rowptr, cnt, bsum, dinv, N);
    k_scatter<<<eblk, TB, 0, stream>>>(src, dst, rowptr, fill, csr_src, E);

    // layer 1
    k_gemmT<<<gemm_blocks, TB, 0, stream>>>(x, W1, bufA, N);
    k_gcn_agg<<<agg_blocks, TB, 0, stream>>>(bufA, csr_src, rowptr, cnt, dinv, b1, bufB, N);

    // layer 2
    k_gemmT<<<gemm_blocks, TB, 0, stream>>>(bufB, W2, bufA, N);
    k_gcn_agg<<<agg_blocks, TB, 0, stream>>>(bufA, csr_src, rowptr, cnt, dinv, b2, bufB, N);

    // pool + head
    k_pool3<<<pool_blocks, 128, 0, stream>>>(bufB, batch, invcnt, pooled, N);
    k_fc1<<<128, 64, 0, stream>>>(pooled, fcW1, fcb1, Z);
    k_bn_out<<<1, 256, 0, stream>>>(Z, gamma, beta, fcW3, fcb3, out);
}